// Round 7
// baseline (598.146 us; speedup 1.0000x reference)
//
#include <hip/hip_runtime.h>

typedef unsigned short u16t;
typedef __attribute__((ext_vector_type(8))) short short8;
typedef __attribute__((ext_vector_type(4))) short short4v;
typedef __attribute__((ext_vector_type(4))) float f32x4;
typedef __attribute__((ext_vector_type(2))) float f32x2;
typedef __attribute__((ext_vector_type(4))) unsigned short u16x4;
typedef __attribute__((ext_vector_type(4))) unsigned int u32x4;
typedef __attribute__((ext_vector_type(2))) unsigned int u32x2;
typedef __attribute__((ext_vector_type(4))) int i32x4;

__device__ __forceinline__ float bf2f(short b) {
  return __uint_as_float(((unsigned)(unsigned short)b) << 16);
}
__device__ __forceinline__ u16t f2bf(float f) {
  unsigned u = __float_as_uint(f);
  u += 0x7FFFu + ((u >> 16) & 1u);  // RNE
  return (u16t)(u >> 16);
}

// jax threefry2x32, key = (0, 42)
__device__ __forceinline__ bool keep_mask(unsigned flat) {
  const unsigned k0 = 0u, k1 = 42u;
  const unsigned k2 = k0 ^ k1 ^ 0x1BD11BDAu;
  unsigned x0 = 0u + k0;
  unsigned x1 = flat + k1;
#define TF_R(r) { x0 += x1; x1 = (x1 << r) | (x1 >> (32 - r)); x1 ^= x0; }
  TF_R(13) TF_R(15) TF_R(26) TF_R(6)  x0 += k1; x1 += k2 + 1u;
  TF_R(17) TF_R(29) TF_R(16) TF_R(24) x0 += k2; x1 += k0 + 2u;
  TF_R(13) TF_R(15) TF_R(26) TF_R(6)  x0 += k0; x1 += k1 + 3u;
  TF_R(17) TF_R(29) TF_R(16) TF_R(24) x0 += k1; x1 += k2 + 4u;
  TF_R(13) TF_R(15) TF_R(26) TF_R(6)  x0 += k2; x1 += k0 + 5u;
#undef TF_R
  return ((x0 ^ x1) >> 31) == 0u;
}

__device__ __forceinline__ void load_lds16(const u16t* g, u16t* l) {
  __builtin_amdgcn_global_load_lds((__attribute__((address_space(1))) void*)g,
                                   (__attribute__((address_space(3))) void*)l,
                                   16, 0, 0);
}

// ---- f32 -> bf16 conversion ----
__global__ void cvt_bf16(const float* __restrict__ s, u16t* __restrict__ d, int n) {
  int i = (blockIdx.x * 256 + threadIdx.x) * 4;
  if (i < n) {
    f32x4 v = *(const f32x4*)&s[i];
    u16x4 o = { f2bf(v.x), f2bf(v.y), f2bf(v.z), f2bf(v.w) };
    *(u16x4*)&d[i] = o;
  }
}

// ---- threefry dropout mask, SLICE-MAJOR coalesced: mask[sl*nn + node] holds
// keep bits for feats [sl*32, sl*32+32) of node. grid = (ceil(nn/256), 16).
__global__ __launch_bounds__(256) void mask_kernel(unsigned* __restrict__ mask, int nn) {
  const int node = blockIdx.x * 256 + threadIdx.x;
  const int sl = blockIdx.y;
  if (node >= nn) return;
  unsigned base = ((unsigned)node * 16u + (unsigned)sl) * 32u;
  unsigned m = 0u;
  for (int k = 0; k < 32; ++k) m |= (keep_mask(base + (unsigned)k) ? 1u : 0u) << k;
  mask[(size_t)sl * nn + node] = m;
}

// ---- CSR build ----
__global__ void count_edges(const int* __restrict__ dst, int E, int* __restrict__ cnt) {
  int e = blockIdx.x * 256 + threadIdx.x;
  if (e < E) atomicAdd(&cnt[dst[e]], 1);
}

// Degree-bin histogram, LDS-aggregated: 16 global atomics per BLOCK.
__global__ __launch_bounds__(256) void bin_hist(const int* __restrict__ cnt,
                                                int* __restrict__ hist, int n) {
  __shared__ int sh[16];
  const int tid = threadIdx.x;
  if (tid < 16) sh[tid] = 0;
  __syncthreads();
  int i = blockIdx.x * 256 + tid;
  if (i < n) {
    int b = (cnt[i] + 8) >> 3;
    atomicAdd(&sh[b < 15 ? b : 15], 1);
  }
  __syncthreads();
  if (tid < 16 && sh[tid] > 0) atomicAdd(&hist[tid], sh[tid]);
}

__global__ void bin_scan(const int* __restrict__ hist, int* __restrict__ binCursor) {
  if (threadIdx.x == 0 && blockIdx.x == 0) {
    int s = 0;
    for (int b = 0; b < 16; ++b) { binCursor[b] = s; s += hist[b]; }
  }
}

// Padded CSR row build + degree-bin permutation (LDS-aggregated bin ranks).
__global__ __launch_bounds__(256) void rowp_build(const int* __restrict__ cnt,
    i32x4* __restrict__ ndr, int* __restrict__ cursor, float* __restrict__ dinv,
    int* __restrict__ gctr, u16t* __restrict__ colu,
    int* __restrict__ binCursor, u16t* __restrict__ perm, int n) {
  __shared__ int sd[256];
  __shared__ int sbase;
  __shared__ int shist[16];
  __shared__ int sbinbase[16];
  const int tid = threadIdx.x;
  const int i = blockIdx.x * 256 + tid;
  int c = (i < n) ? cnt[i] : 0;
  int cs = c + 1;
  int p = (i < n) ? ((cs + 7) & ~7) : 0;
  int v = p;
  sd[tid] = v;
  if (tid < 16) shist[tid] = 0;
  __syncthreads();
  for (int o = 1; o < 256; o <<= 1) {
    int t2 = (tid >= o) ? sd[tid - o] : 0;
    __syncthreads();
    v += t2;
    sd[tid] = v;
    __syncthreads();
  }
  int b = p >> 3;
  b = b < 15 ? b : 15;
  int rank = 0;
  if (i < n) rank = atomicAdd(&shist[b], 1);
  if (tid == 255) sbase = atomicAdd(gctr, v);
  __syncthreads();
  if (tid < 16) sbinbase[tid] = (shist[tid] > 0) ? atomicAdd(&binCursor[tid], shist[tid]) : 0;
  __syncthreads();
  if (i < n) {
    int start = sbase + v - p;
    cursor[i] = start;
    float dv = rsqrtf((float)cs);
    dinv[i] = dv;
    i32x4 r;
    r[0] = start; r[1] = start + p; r[2] = __float_as_int(dv); r[3] = 0;
    ndr[i] = r;
    colu[start + c] = (u16t)i;                                  // self entry
    for (int q = c + 1; q < p; ++q) colu[start + q] = (u16t)n;  // dummies -> zero row
    perm[sbinbase[b] + rank] = (u16t)i;
  }
}

__global__ void fill_csr(const int* __restrict__ src, const int* __restrict__ dst, int E,
                         int* __restrict__ cursor, u16t* __restrict__ col) {
  int e = blockIdx.x * 256 + threadIdx.x;
  if (e < E) {
    int d = dst[e];
    int pos = atomicAdd(&cursor[d], 1);
    col[pos] = (u16t)src[e];
  }
}

// ---- bf16 GEMM, SLICE-MAJOR output, rows PRE-SCALED by dinv[row]; rows >=
// Nclamp written as exact zeros. Epilogue stages the 128x128 tile through LDS
// (two 128x64 passes) and writes each 32-col slice as contiguous dwordx4 runs.
__global__ __launch_bounds__(256) void gemm_bt_sl(const u16t* __restrict__ A,
                                                  const u16t* __restrict__ B,
                                                  u16t* __restrict__ C,
                                                  int K, int Mrows,
                                                  const float* __restrict__ dinv,
                                                  int Nclamp) {
  __shared__ __align__(16) u16t lbuf[128 * 72];  // K-loop: lA=lbuf, lB=lbuf+4096
  u16t* lA = lbuf;
  u16t* lB = lbuf + 4096;
  const int tid = threadIdx.x;
  const int wave = tid >> 6, lane = tid & 63;
  const int wm = (wave & 1) * 64, wn = (wave >> 1) * 64;
  const int lrow = lane & 15, lq = lane >> 4;
  const u16t* Ab = A + (size_t)blockIdx.x * 128 * K;
  const u16t* Bb = B + (size_t)blockIdx.y * 128 * K;
  const int r0 = tid >> 2, c0 = (tid & 3) * 8;
  const int ldsOff = __builtin_amdgcn_readfirstlane((tid >> 6) * 512);

  f32x4 acc[4][4];
  const f32x4 zero = {0.f, 0.f, 0.f, 0.f};
#pragma unroll
  for (int mi = 0; mi < 4; ++mi)
#pragma unroll
    for (int ni = 0; ni < 4; ++ni) acc[mi][ni] = zero;

  for (int kt = 0; kt < K; kt += 32) {
    __syncthreads();
    load_lds16(Ab + (size_t)r0 * K + kt + c0, &lA[ldsOff]);
    load_lds16(Ab + (size_t)(r0 + 64) * K + kt + c0, &lA[2048 + ldsOff]);
    load_lds16(Bb + (size_t)r0 * K + kt + c0, &lB[ldsOff]);
    load_lds16(Bb + (size_t)(r0 + 64) * K + kt + c0, &lB[2048 + ldsOff]);
    __syncthreads();
    short8 af[4], bfr[4];
#pragma unroll
    for (int mi = 0; mi < 4; ++mi)
      af[mi] = *(const short8*)&lA[(wm + mi * 16 + lrow) * 32 + lq * 8];
#pragma unroll
    for (int ni = 0; ni < 4; ++ni)
      bfr[ni] = *(const short8*)&lB[(wn + ni * 16 + lrow) * 32 + lq * 8];
#pragma unroll
    for (int mi = 0; mi < 4; ++mi)
#pragma unroll
      for (int ni = 0; ni < 4; ++ni)
        acc[mi][ni] = __builtin_amdgcn_mfma_f32_16x16x32_bf16(af[mi], bfr[ni], acc[mi][ni], 0, 0, 0);
  }

  const int crow_base = blockIdx.x * 128;
  const int crow0 = crow_base + wm + lq * 4;
#pragma unroll
  for (int h = 0; h < 2; ++h) {
    __syncthreads();
    if ((wave >> 1) == h) {
#pragma unroll
      for (int mi = 0; mi < 4; ++mi)
#pragma unroll
        for (int r = 0; r < 4; ++r) {
          const int row = crow0 + mi * 16 + r;
          const float dr = (row < Nclamp) ? dinv[row] : 0.f;
          const int trow = wm + mi * 16 + lq * 4 + r;  // 0..127
#pragma unroll
          for (int ni = 0; ni < 4; ++ni)
            lbuf[trow * 72 + ni * 16 + lrow] = f2bf(dr * acc[mi][ni][r]);
        }
    }
    __syncthreads();
#pragma unroll
    for (int s = 0; s < 2; ++s) {
      const int slice = blockIdx.y * 4 + h * 2 + s;
      char* dst = (char*)C + ((size_t)slice * Mrows + crow_base) * 64;
      const char* srcl = (const char*)lbuf;
#pragma unroll
      for (int k2 = 0; k2 < 2; ++k2) {
        const int idx = tid + 256 * k2;     // 0..511
        const int row = idx >> 2, seg = idx & 3;
        *(u32x4*)(dst + row * 64 + seg * 16) =
            *(const u32x4*)(srcl + row * 144 + s * 64 + seg * 16);
      }
    }
  }
}

// 8 edges, 4 lanes/node: each lane loads 16B (8 feats) per edge row; 4 lanes
// cover the 64B row. Uniform base + 32-bit voffset, pk_add accumulate.
__device__ __forceinline__ void gather8w(const char* __restrict__ Tb, u32x4 cw,
                                         unsigned flb, f32x2 acc[4]) {
  unsigned off[8];
#pragma unroll
  for (int q = 0; q < 4; ++q) {
    off[2 * q]     = ((cw[q] & 0xFFFFu) << 6) | flb;
    off[2 * q + 1] = ((cw[q] >> 16) << 6) | flb;
  }
  u32x4 w[8];
#pragma unroll
  for (int q = 0; q < 8; ++q) w[q] = *(const u32x4*)(Tb + (size_t)off[q]);
#pragma unroll
  for (int q = 0; q < 8; ++q)
#pragma unroll
    for (int d = 0; d < 4; ++d) {
      f32x2 v = { __uint_as_float(w[q][d] << 16),
                  __uint_as_float(w[q][d] & 0xFFFF0000u) };
      acc[d] += v;
    }
}

// ---- sliced propagate layer 1: 4 lanes/node (16B each), 64 nodes/block,
// degree-binned order, padded CSR.
__global__ __launch_bounds__(256) void prop1_kernel(const u16t* __restrict__ T0,
    const u16t* __restrict__ colu, const i32x4* __restrict__ ndr,
    const u16t* __restrict__ perm, const float* __restrict__ b1,
    const unsigned* __restrict__ kmask,
    float* __restrict__ embf, u16t* __restrict__ embb, int n, int Mrows, int chunks) {
  const int t = threadIdx.x;
  const unsigned flb = (unsigned)(t & 3) * 16u;  // byte offset of lane's 8 feats
  const int fl8 = (t & 3) * 8;
  const int bid = blockIdx.x;
  const int half = chunks << 3;
  const int phase = bid >= half;
  const int rem = bid - (phase ? half : 0);
  const int sl = (rem & 7) + (phase << 3);
  const int slot = (rem >> 3) * 64 + (t >> 2);
  if (slot >= n) return;
  const int i = (int)perm[slot];

  const char* Tb = (const char*)T0 + (size_t)sl * ((size_t)Mrows * 64);
  const i32x4 nd = ndr[i];
  const float di = __int_as_float(nd[2]);
  f32x2 a[4] = {{0.f, 0.f}, {0.f, 0.f}, {0.f, 0.f}, {0.f, 0.f}};

  int e = nd[0];
  const int end = nd[1];
  u32x4 cw = *(const u32x4*)&colu[e];
  e += 8;
  while (e < end) {
    u32x4 nw = *(const u32x4*)&colu[e];
    e += 8;
    gather8w(Tb, cw, flb, a);
    cw = nw;
  }
  gather8w(Tb, cw, flb, a);

  const int f = sl * 32 + fl8;
  const unsigned km = kmask[(size_t)sl * n + i] >> fl8;
  float acc[8] = {a[0].x, a[0].y, a[1].x, a[1].y, a[2].x, a[2].y, a[3].x, a[3].y};
  f32x4 o0, o1;
  short8 ob;
#pragma unroll
  for (int j = 0; j < 8; ++j) {
    float h = di * acc[j] + b1[f + j];
    h = fmaxf(h, 0.f);
    float eb = ((km >> j) & 1u) ? 2.f * h : 0.f;
    if (j < 4) o0[j] = eb; else o1[j - 4] = eb;
    ob[j] = (short)f2bf(eb);
  }
  __builtin_nontemporal_store(o0, (f32x4*)&embf[(size_t)i * 512 + f]);
  __builtin_nontemporal_store(o1, (f32x4*)&embf[(size_t)i * 512 + f + 4]);
  __builtin_nontemporal_store(ob, (short8*)&embb[(size_t)i * 512 + f]);
}

// ---- sliced propagate layer 2 (8 slices, 1 phase), 4 lanes/node ----
__global__ __launch_bounds__(256) void prop2_kernel(const u16t* __restrict__ T0,
    const u16t* __restrict__ colu, const i32x4* __restrict__ ndr,
    const u16t* __restrict__ perm, const float* __restrict__ b2,
    float* __restrict__ outp, int n, int Mrows) {
  const int t = threadIdx.x;
  const unsigned flb = (unsigned)(t & 3) * 16u;
  const int fl8 = (t & 3) * 8;
  const int bid = blockIdx.x;
  const int sl = bid & 7;
  const int slot = (bid >> 3) * 64 + (t >> 2);
  if (slot >= n) return;
  const int i = (int)perm[slot];

  const char* Tb = (const char*)T0 + (size_t)sl * ((size_t)Mrows * 64);
  const i32x4 nd = ndr[i];
  const float di = __int_as_float(nd[2]);
  f32x2 a[4] = {{0.f, 0.f}, {0.f, 0.f}, {0.f, 0.f}, {0.f, 0.f}};

  int e = nd[0];
  const int end = nd[1];
  u32x4 cw = *(const u32x4*)&colu[e];
  e += 8;
  while (e < end) {
    u32x4 nw = *(const u32x4*)&colu[e];
    e += 8;
    gather8w(Tb, cw, flb, a);
    cw = nw;
  }
  gather8w(Tb, cw, flb, a);

  const int f = sl * 32 + fl8;
  float acc[8] = {a[0].x, a[0].y, a[1].x, a[1].y, a[2].x, a[2].y, a[3].x, a[3].y};
  f32x4 o0, o1;
#pragma unroll
  for (int j = 0; j < 8; ++j) {
    float v = di * acc[j] + b2[f + j];
    if (j < 4) o0[j] = v; else o1[j - 4] = v;
  }
  __builtin_nontemporal_store(o0, (f32x4*)&outp[(size_t)i * 256 + f]);
  __builtin_nontemporal_store(o1, (f32x4*)&outp[(size_t)i * 256 + f + 4]);
}

extern "C" void kernel_launch(void* const* d_in, const int* in_sizes, int n_in,
                              void* d_out, int out_size, void* d_ws, size_t ws_size,
                              hipStream_t stream) {
  (void)n_in; (void)out_size; (void)ws_size;
  const float* x  = (const float*)d_in[0];
  const int*   ei = (const int*)d_in[1];    // [2][E]: src row then dst row
  const float* W1 = (const float*)d_in[2];
  const float* b1 = (const float*)d_in[3];
  const float* W2 = (const float*)d_in[4];
  const float* b2 = (const float*)d_in[5];

  const int Nn = in_sizes[0] / 512;             // 50000
  const int E  = in_sizes[1] / 2;               // 800000
  const int Mpad = ((Nn + 127) / 128) * 128;    // 50048
  const int K = 512;
  const int CH = (Nn + 63) / 64;                // 64 nodes per slice-block

  char* ws = (char*)d_ws;
  size_t off = 0;
  auto take = [&](size_t bytes) -> char* {
    char* p = ws + off;
    off += (bytes + 255) & ~(size_t)255;
    return p;
  };
  u16t* xb   = (u16t*)take((size_t)Mpad * 512 * 2);      // x bf16; reused as emb bf16
  u16t* y1s  = (u16t*)take((size_t)16 * Mpad * 32 * 2);  // y1 slice-major; zs aliases
  u16t* W1b  = (u16t*)take((size_t)512 * 512 * 2);
  u16t* W2b  = (u16t*)take((size_t)256 * 512 * 2);
  // cnt[Nn] | gctr | hist[16] | binCursor[16]
  int*   cnt    = (int*)take((size_t)(Nn + 33) * 4);
  int*   cursor = (int*)take((size_t)Nn * 4);
  float* dinv   = (float*)take((size_t)Nn * 4);
  i32x4* ndr    = (i32x4*)take((size_t)Nn * 16);         // {start, end, dinv, 0}
  u16t*  perm   = (u16t*)take((size_t)Nn * 2);           // degree-binned node order
  u16t*  colu   = (u16t*)take((size_t)(E + 8 * (Nn + 1) + 64) * 2);  // padded CSR
  unsigned* kmask = (unsigned*)take((size_t)Nn * 16 * 4);  // slice-major keep bits

  float* embf = (float*)d_out;                       // [Nn,512]
  float* outf = (float*)d_out + (size_t)Nn * 512;    // [Nn,256]

  int* gctr      = cnt + Nn;
  int* hist      = cnt + Nn + 1;
  int* binCursor = cnt + Nn + 17;

  hipMemsetAsync(cnt, 0, (size_t)(Nn + 33) * 4, stream);

  const int n1 = Nn * 512;
  cvt_bf16<<<(n1 / 4 + 255) / 256, 256, 0, stream>>>(x, xb, n1);
  cvt_bf16<<<(512 * 512 / 4 + 255) / 256, 256, 0, stream>>>(W1, W1b, 512 * 512);
  cvt_bf16<<<(256 * 512 / 4 + 255) / 256, 256, 0, stream>>>(W2, W2b, 256 * 512);
  mask_kernel<<<dim3((Nn + 255) / 256, 16), 256, 0, stream>>>(kmask, Nn);

  count_edges<<<(E + 255) / 256, 256, 0, stream>>>(ei + E, E, cnt);
  bin_hist<<<(Nn + 255) / 256, 256, 0, stream>>>(cnt, hist, Nn);
  bin_scan<<<1, 64, 0, stream>>>(hist, binCursor);
  rowp_build<<<(Nn + 255) / 256, 256, 0, stream>>>(cnt, ndr, cursor, dinv, gctr,
                                                   colu, binCursor, perm, Nn);
  fill_csr<<<(E + 255) / 256, 256, 0, stream>>>(ei, ei + E, E, cursor, colu);

  // layer 1: y1 = dinv * (x @ W1^T), slice-major; then XCD-sliced propagate
  dim3 g1(Mpad / 128, 4);
  gemm_bt_sl<<<g1, 256, 0, stream>>>(xb, W1b, y1s, K, Mpad, dinv, Nn);
  prop1_kernel<<<16 * CH, 256, 0, stream>>>(y1s, colu, ndr, perm, b1, kmask,
                                            embf, xb /* emb bf16 */, Nn, Mpad, CH);

  // layer 2: z = dinv * (emb @ W2^T), slice-major; then propagate + b2
  u16t* zs = y1s;  // alias: y1 dead after prop1
  dim3 g2(Mpad / 128, 2);
  gemm_bt_sl<<<g2, 256, 0, stream>>>(xb, W2b, zs, K, Mpad, dinv, Nn);
  prop2_kernel<<<8 * CH, 256, 0, stream>>>(zs, colu, ndr, perm, b2, outf, Nn, Mpad);
}

// Round 8
// 592.595 us; speedup vs baseline: 1.0094x; 1.0094x over previous
//
#include <hip/hip_runtime.h>

typedef unsigned short u16t;
typedef __attribute__((ext_vector_type(8))) short short8;
typedef __attribute__((ext_vector_type(4))) short short4v;
typedef __attribute__((ext_vector_type(4))) float f32x4;
typedef __attribute__((ext_vector_type(2))) float f32x2;
typedef __attribute__((ext_vector_type(4))) unsigned short u16x4;
typedef __attribute__((ext_vector_type(4))) unsigned int u32x4;
typedef __attribute__((ext_vector_type(2))) unsigned int u32x2;
typedef __attribute__((ext_vector_type(4))) int i32x4;

__device__ __forceinline__ float bf2f(short b) {
  return __uint_as_float(((unsigned)(unsigned short)b) << 16);
}
__device__ __forceinline__ u16t f2bf(float f) {
  unsigned u = __float_as_uint(f);
  u += 0x7FFFu + ((u >> 16) & 1u);  // RNE
  return (u16t)(u >> 16);
}

// jax threefry2x32, key = (0, 42)
__device__ __forceinline__ bool keep_mask(unsigned flat) {
  const unsigned k0 = 0u, k1 = 42u;
  const unsigned k2 = k0 ^ k1 ^ 0x1BD11BDAu;
  unsigned x0 = 0u + k0;
  unsigned x1 = flat + k1;
#define TF_R(r) { x0 += x1; x1 = (x1 << r) | (x1 >> (32 - r)); x1 ^= x0; }
  TF_R(13) TF_R(15) TF_R(26) TF_R(6)  x0 += k1; x1 += k2 + 1u;
  TF_R(17) TF_R(29) TF_R(16) TF_R(24) x0 += k2; x1 += k0 + 2u;
  TF_R(13) TF_R(15) TF_R(26) TF_R(6)  x0 += k0; x1 += k1 + 3u;
  TF_R(17) TF_R(29) TF_R(16) TF_R(24) x0 += k1; x1 += k2 + 4u;
  TF_R(13) TF_R(15) TF_R(26) TF_R(6)  x0 += k2; x1 += k0 + 5u;
#undef TF_R
  return ((x0 ^ x1) >> 31) == 0u;
}

__device__ __forceinline__ void load_lds16(const u16t* g, u16t* l) {
  __builtin_amdgcn_global_load_lds((__attribute__((address_space(1))) void*)g,
                                   (__attribute__((address_space(3))) void*)l,
                                   16, 0, 0);
}

// ---- f32 -> bf16 conversion ----
__global__ void cvt_bf16(const float* __restrict__ s, u16t* __restrict__ d, int n) {
  int i = (blockIdx.x * 256 + threadIdx.x) * 4;
  if (i < n) {
    f32x4 v = *(const f32x4*)&s[i];
    u16x4 o = { f2bf(v.x), f2bf(v.y), f2bf(v.z), f2bf(v.w) };
    *(u16x4*)&d[i] = o;
  }
}

// ---- threefry dropout mask, SLICE-MAJOR coalesced: mask[sl*nn + node] ----
__global__ __launch_bounds__(256) void mask_kernel(unsigned* __restrict__ mask, int nn) {
  const int node = blockIdx.x * 256 + threadIdx.x;
  const int sl = blockIdx.y;
  if (node >= nn) return;
  unsigned base = ((unsigned)node * 16u + (unsigned)sl) * 32u;
  unsigned m = 0u;
  for (int k = 0; k < 32; ++k) m |= (keep_mask(base + (unsigned)k) ? 1u : 0u) << k;
  mask[(size_t)sl * nn + node] = m;
}

// ---- CSR build ----
__global__ void count_edges(const int* __restrict__ dst, int E, int* __restrict__ cnt) {
  int e = blockIdx.x * 256 + threadIdx.x;
  if (e < E) atomicAdd(&cnt[dst[e]], 1);
}

// Degree-bin histogram, LDS-aggregated: 16 global atomics per BLOCK.
__global__ __launch_bounds__(256) void bin_hist(const int* __restrict__ cnt,
                                                int* __restrict__ hist, int n) {
  __shared__ int sh[16];
  const int tid = threadIdx.x;
  if (tid < 16) sh[tid] = 0;
  __syncthreads();
  int i = blockIdx.x * 256 + tid;
  if (i < n) {
    int b = (cnt[i] + 8) >> 3;
    atomicAdd(&sh[b < 15 ? b : 15], 1);
  }
  __syncthreads();
  if (tid < 16 && sh[tid] > 0) atomicAdd(&hist[tid], sh[tid]);
}

// DESCENDING bin bases (LPT): highest-degree bin gets slot 0, so the longest
// propagate blocks are dispatched FIRST -> no straggler tail.
__global__ void bin_scan(const int* __restrict__ hist, int* __restrict__ binCursor) {
  if (threadIdx.x == 0 && blockIdx.x == 0) {
    int s = 0;
    for (int b = 15; b >= 0; --b) { binCursor[b] = s; s += hist[b]; }
  }
}

// Padded CSR row build + degree-bin permutation (LDS-aggregated bin ranks).
__global__ __launch_bounds__(256) void rowp_build(const int* __restrict__ cnt,
    i32x4* __restrict__ ndr, int* __restrict__ cursor, float* __restrict__ dinv,
    int* __restrict__ gctr, u16t* __restrict__ colu,
    int* __restrict__ binCursor, u16t* __restrict__ perm, int n) {
  __shared__ int sd[256];
  __shared__ int sbase;
  __shared__ int shist[16];
  __shared__ int sbinbase[16];
  const int tid = threadIdx.x;
  const int i = blockIdx.x * 256 + tid;
  int c = (i < n) ? cnt[i] : 0;
  int cs = c + 1;
  int p = (i < n) ? ((cs + 7) & ~7) : 0;
  int v = p;
  sd[tid] = v;
  if (tid < 16) shist[tid] = 0;
  __syncthreads();
  for (int o = 1; o < 256; o <<= 1) {
    int t2 = (tid >= o) ? sd[tid - o] : 0;
    __syncthreads();
    v += t2;
    sd[tid] = v;
    __syncthreads();
  }
  int b = p >> 3;
  b = b < 15 ? b : 15;
  int rank = 0;
  if (i < n) rank = atomicAdd(&shist[b], 1);
  if (tid == 255) sbase = atomicAdd(gctr, v);
  __syncthreads();
  if (tid < 16) sbinbase[tid] = (shist[tid] > 0) ? atomicAdd(&binCursor[tid], shist[tid]) : 0;
  __syncthreads();
  if (i < n) {
    int start = sbase + v - p;
    cursor[i] = start;
    float dv = rsqrtf((float)cs);
    dinv[i] = dv;
    i32x4 r;
    r[0] = start; r[1] = start + p; r[2] = __float_as_int(dv); r[3] = 0;
    ndr[i] = r;
    colu[start + c] = (u16t)i;                                  // self entry
    for (int q = c + 1; q < p; ++q) colu[start + q] = (u16t)n;  // dummies -> zero row
    perm[sbinbase[b] + rank] = (u16t)i;
  }
}

__global__ void fill_csr(const int* __restrict__ src, const int* __restrict__ dst, int E,
                         int* __restrict__ cursor, u16t* __restrict__ col) {
  int e = blockIdx.x * 256 + threadIdx.x;
  if (e < E) {
    int d = dst[e];
    int pos = atomicAdd(&cursor[d], 1);
    col[pos] = (u16t)src[e];
  }
}

// ---- bf16 GEMM, SLICE-MAJOR output, rows PRE-SCALED by dinv[row];
// rows >= Nclamp written as exact zeros (zero row for CSR dummies).
// Direct scalar slice-major epilogue (r6 form — LDS-staged variant regressed).
__global__ __launch_bounds__(256) void gemm_bt_sl(const u16t* __restrict__ A,
                                                  const u16t* __restrict__ B,
                                                  u16t* __restrict__ C,
                                                  int K, int Mrows,
                                                  const float* __restrict__ dinv,
                                                  int Nclamp) {
  __shared__ __align__(16) u16t lA[128 * 32];
  __shared__ __align__(16) u16t lB[128 * 32];
  const int tid = threadIdx.x;
  const int wave = tid >> 6, lane = tid & 63;
  const int wm = (wave & 1) * 64, wn = (wave >> 1) * 64;
  const int lrow = lane & 15, lq = lane >> 4;
  const u16t* Ab = A + (size_t)blockIdx.x * 128 * K;
  const u16t* Bb = B + (size_t)blockIdx.y * 128 * K;
  const int r0 = tid >> 2, c0 = (tid & 3) * 8;
  const int ldsOff = __builtin_amdgcn_readfirstlane((tid >> 6) * 512);

  f32x4 acc[4][4];
  const f32x4 zero = {0.f, 0.f, 0.f, 0.f};
#pragma unroll
  for (int mi = 0; mi < 4; ++mi)
#pragma unroll
    for (int ni = 0; ni < 4; ++ni) acc[mi][ni] = zero;

  for (int kt = 0; kt < K; kt += 32) {
    __syncthreads();
    load_lds16(Ab + (size_t)r0 * K + kt + c0, &lA[ldsOff]);
    load_lds16(Ab + (size_t)(r0 + 64) * K + kt + c0, &lA[2048 + ldsOff]);
    load_lds16(Bb + (size_t)r0 * K + kt + c0, &lB[ldsOff]);
    load_lds16(Bb + (size_t)(r0 + 64) * K + kt + c0, &lB[2048 + ldsOff]);
    __syncthreads();
    short8 af[4], bfr[4];
#pragma unroll
    for (int mi = 0; mi < 4; ++mi)
      af[mi] = *(const short8*)&lA[(wm + mi * 16 + lrow) * 32 + lq * 8];
#pragma unroll
    for (int ni = 0; ni < 4; ++ni)
      bfr[ni] = *(const short8*)&lB[(wn + ni * 16 + lrow) * 32 + lq * 8];
#pragma unroll
    for (int mi = 0; mi < 4; ++mi)
#pragma unroll
      for (int ni = 0; ni < 4; ++ni)
        acc[mi][ni] = __builtin_amdgcn_mfma_f32_16x16x32_bf16(af[mi], bfr[ni], acc[mi][ni], 0, 0, 0);
  }

  const int crow0 = blockIdx.x * 128 + wm + lq * 4;
  const int ccol0 = blockIdx.y * 128 + wn + lrow;
#pragma unroll
  for (int mi = 0; mi < 4; ++mi)
#pragma unroll
    for (int r = 0; r < 4; ++r) {
      const int row = crow0 + mi * 16 + r;
      const float dr = (row < Nclamp) ? dinv[row] : 0.f;
#pragma unroll
      for (int ni = 0; ni < 4; ++ni) {
        int cc = ccol0 + ni * 16;
        size_t idx = ((size_t)(cc >> 5) * Mrows + row) * 32 + (cc & 31);
        C[idx] = f2bf(dr * acc[mi][ni][r]);
      }
    }
}

// 8 edges, 4 lanes/node: each lane loads 16B (8 feats) per edge row; 4 lanes
// cover the 64B row. Uniform base + 32-bit voffset, pk_add accumulate.
__device__ __forceinline__ void gather8w(const char* __restrict__ Tb, u32x4 cw,
                                         unsigned flb, f32x2 acc[4]) {
  unsigned off[8];
#pragma unroll
  for (int q = 0; q < 4; ++q) {
    off[2 * q]     = ((cw[q] & 0xFFFFu) << 6) | flb;
    off[2 * q + 1] = ((cw[q] >> 16) << 6) | flb;
  }
  u32x4 w[8];
#pragma unroll
  for (int q = 0; q < 8; ++q) w[q] = *(const u32x4*)(Tb + (size_t)off[q]);
#pragma unroll
  for (int q = 0; q < 8; ++q)
#pragma unroll
    for (int d = 0; d < 4; ++d) {
      f32x2 v = { __uint_as_float(w[q][d] << 16),
                  __uint_as_float(w[q][d] & 0xFFFF0000u) };
      acc[d] += v;
    }
}

// ---- sliced propagate layer 1: 4 lanes/node (16B each), 64 nodes/block,
// LPT degree-binned order, padded CSR.
__global__ __launch_bounds__(256) void prop1_kernel(const u16t* __restrict__ T0,
    const u16t* __restrict__ colu, const i32x4* __restrict__ ndr,
    const u16t* __restrict__ perm, const float* __restrict__ b1,
    const unsigned* __restrict__ kmask,
    float* __restrict__ embf, u16t* __restrict__ embb, int n, int Mrows, int chunks) {
  const int t = threadIdx.x;
  const unsigned flb = (unsigned)(t & 3) * 16u;  // byte offset of lane's 8 feats
  const int fl8 = (t & 3) * 8;
  const int bid = blockIdx.x;
  const int half = chunks << 3;
  const int phase = bid >= half;
  const int rem = bid - (phase ? half : 0);
  const int sl = (rem & 7) + (phase << 3);
  const int slot = (rem >> 3) * 64 + (t >> 2);
  if (slot >= n) return;
  const int i = (int)perm[slot];

  const char* Tb = (const char*)T0 + (size_t)sl * ((size_t)Mrows * 64);
  const i32x4 nd = ndr[i];
  const float di = __int_as_float(nd[2]);
  f32x2 a[4] = {{0.f, 0.f}, {0.f, 0.f}, {0.f, 0.f}, {0.f, 0.f}};

  int e = nd[0];
  const int end = nd[1];
  u32x4 cw = *(const u32x4*)&colu[e];
  e += 8;
  while (e < end) {
    u32x4 nw = *(const u32x4*)&colu[e];
    e += 8;
    gather8w(Tb, cw, flb, a);
    cw = nw;
  }
  gather8w(Tb, cw, flb, a);

  const int f = sl * 32 + fl8;
  const unsigned km = kmask[(size_t)sl * n + i] >> fl8;
  float acc[8] = {a[0].x, a[0].y, a[1].x, a[1].y, a[2].x, a[2].y, a[3].x, a[3].y};
  f32x4 o0, o1;
  short8 ob;
#pragma unroll
  for (int j = 0; j < 8; ++j) {
    float h = di * acc[j] + b1[f + j];
    h = fmaxf(h, 0.f);
    float eb = ((km >> j) & 1u) ? 2.f * h : 0.f;
    if (j < 4) o0[j] = eb; else o1[j - 4] = eb;
    ob[j] = (short)f2bf(eb);
  }
  __builtin_nontemporal_store(o0, (f32x4*)&embf[(size_t)i * 512 + f]);
  __builtin_nontemporal_store(o1, (f32x4*)&embf[(size_t)i * 512 + f + 4]);
  __builtin_nontemporal_store(ob, (short8*)&embb[(size_t)i * 512 + f]);
}

// ---- sliced propagate layer 2 (8 slices, 1 phase), 4 lanes/node ----
__global__ __launch_bounds__(256) void prop2_kernel(const u16t* __restrict__ T0,
    const u16t* __restrict__ colu, const i32x4* __restrict__ ndr,
    const u16t* __restrict__ perm, const float* __restrict__ b2,
    float* __restrict__ outp, int n, int Mrows) {
  const int t = threadIdx.x;
  const unsigned flb = (unsigned)(t & 3) * 16u;
  const int fl8 = (t & 3) * 8;
  const int bid = blockIdx.x;
  const int sl = bid & 7;
  const int slot = (bid >> 3) * 64 + (t >> 2);
  if (slot >= n) return;
  const int i = (int)perm[slot];

  const char* Tb = (const char*)T0 + (size_t)sl * ((size_t)Mrows * 64);
  const i32x4 nd = ndr[i];
  const float di = __int_as_float(nd[2]);
  f32x2 a[4] = {{0.f, 0.f}, {0.f, 0.f}, {0.f, 0.f}, {0.f, 0.f}};

  int e = nd[0];
  const int end = nd[1];
  u32x4 cw = *(const u32x4*)&colu[e];
  e += 8;
  while (e < end) {
    u32x4 nw = *(const u32x4*)&colu[e];
    e += 8;
    gather8w(Tb, cw, flb, a);
    cw = nw;
  }
  gather8w(Tb, cw, flb, a);

  const int f = sl * 32 + fl8;
  float acc[8] = {a[0].x, a[0].y, a[1].x, a[1].y, a[2].x, a[2].y, a[3].x, a[3].y};
  f32x4 o0, o1;
#pragma unroll
  for (int j = 0; j < 8; ++j) {
    float v = di * acc[j] + b2[f + j];
    if (j < 4) o0[j] = v; else o1[j - 4] = v;
  }
  __builtin_nontemporal_store(o0, (f32x4*)&outp[(size_t)i * 256 + f]);
  __builtin_nontemporal_store(o1, (f32x4*)&outp[(size_t)i * 256 + f + 4]);
}

extern "C" void kernel_launch(void* const* d_in, const int* in_sizes, int n_in,
                              void* d_out, int out_size, void* d_ws, size_t ws_size,
                              hipStream_t stream) {
  (void)n_in; (void)out_size; (void)ws_size;
  const float* x  = (const float*)d_in[0];
  const int*   ei = (const int*)d_in[1];    // [2][E]: src row then dst row
  const float* W1 = (const float*)d_in[2];
  const float* b1 = (const float*)d_in[3];
  const float* W2 = (const float*)d_in[4];
  const float* b2 = (const float*)d_in[5];

  const int Nn = in_sizes[0] / 512;             // 50000
  const int E  = in_sizes[1] / 2;               // 800000
  const int Mpad = ((Nn + 127) / 128) * 128;    // 50048
  const int K = 512;
  const int CH = (Nn + 63) / 64;                // 64 nodes per slice-block

  char* ws = (char*)d_ws;
  size_t off = 0;
  auto take = [&](size_t bytes) -> char* {
    char* p = ws + off;
    off += (bytes + 255) & ~(size_t)255;
    return p;
  };
  u16t* xb   = (u16t*)take((size_t)Mpad * 512 * 2);      // x bf16; reused as emb bf16
  u16t* y1s  = (u16t*)take((size_t)16 * Mpad * 32 * 2);  // y1 slice-major; zs aliases
  u16t* W1b  = (u16t*)take((size_t)512 * 512 * 2);
  u16t* W2b  = (u16t*)take((size_t)256 * 512 * 2);
  // cnt[Nn] | gctr | hist[16] | binCursor[16]
  int*   cnt    = (int*)take((size_t)(Nn + 33) * 4);
  int*   cursor = (int*)take((size_t)Nn * 4);
  float* dinv   = (float*)take((size_t)Nn * 4);
  i32x4* ndr    = (i32x4*)take((size_t)Nn * 16);         // {start, end, dinv, 0}
  u16t*  perm   = (u16t*)take((size_t)Nn * 2);           // LPT degree-binned order
  u16t*  colu   = (u16t*)take((size_t)(E + 8 * (Nn + 1) + 64) * 2);  // padded CSR
  unsigned* kmask = (unsigned*)take((size_t)Nn * 16 * 4);  // slice-major keep bits

  float* embf = (float*)d_out;                       // [Nn,512]
  float* outf = (float*)d_out + (size_t)Nn * 512;    // [Nn,256]

  int* gctr      = cnt + Nn;
  int* hist      = cnt + Nn + 1;
  int* binCursor = cnt + Nn + 17;

  hipMemsetAsync(cnt, 0, (size_t)(Nn + 33) * 4, stream);

  const int n1 = Nn * 512;
  cvt_bf16<<<(n1 / 4 + 255) / 256, 256, 0, stream>>>(x, xb, n1);
  cvt_bf16<<<(512 * 512 / 4 + 255) / 256, 256, 0, stream>>>(W1, W1b, 512 * 512);
  cvt_bf16<<<(256 * 512 / 4 + 255) / 256, 256, 0, stream>>>(W2, W2b, 256 * 512);
  mask_kernel<<<dim3((Nn + 255) / 256, 16), 256, 0, stream>>>(kmask, Nn);

  count_edges<<<(E + 255) / 256, 256, 0, stream>>>(ei + E, E, cnt);
  bin_hist<<<(Nn + 255) / 256, 256, 0, stream>>>(cnt, hist, Nn);
  bin_scan<<<1, 64, 0, stream>>>(hist, binCursor);
  rowp_build<<<(Nn + 255) / 256, 256, 0, stream>>>(cnt, ndr, cursor, dinv, gctr,
                                                   colu, binCursor, perm, Nn);
  fill_csr<<<(E + 255) / 256, 256, 0, stream>>>(ei, ei + E, E, cursor, colu);

  // layer 1: y1 = dinv * (x @ W1^T), slice-major; then XCD-sliced propagate
  dim3 g1(Mpad / 128, 4);
  gemm_bt_sl<<<g1, 256, 0, stream>>>(xb, W1b, y1s, K, Mpad, dinv, Nn);
  prop1_kernel<<<16 * CH, 256, 0, stream>>>(y1s, colu, ndr, perm, b1, kmask,
                                            embf, xb /* emb bf16 */, Nn, Mpad, CH);

  // layer 2: z = dinv * (emb @ W2^T), slice-major; then propagate + b2
  u16t* zs = y1s;  // alias: y1 dead after prop1
  dim3 g2(Mpad / 128, 2);
  gemm_bt_sl<<<g2, 256, 0, stream>>>(xb, W2b, zs, K, Mpad, dinv, Nn);
  prop2_kernel<<<8 * CH, 256, 0, stream>>>(zs, colu, ndr, perm, b2, outf, Nn, Mpad);
}

// Round 9
// 583.615 us; speedup vs baseline: 1.0249x; 1.0154x over previous
//
#include <hip/hip_runtime.h>

typedef unsigned short u16t;
typedef __attribute__((ext_vector_type(8))) short short8;
typedef __attribute__((ext_vector_type(4))) short short4v;
typedef __attribute__((ext_vector_type(4))) float f32x4;
typedef __attribute__((ext_vector_type(2))) float f32x2;
typedef __attribute__((ext_vector_type(4))) unsigned short u16x4;
typedef __attribute__((ext_vector_type(4))) unsigned int u32x4;
typedef __attribute__((ext_vector_type(2))) unsigned int u32x2;
typedef __attribute__((ext_vector_type(4))) int i32x4;

__device__ __forceinline__ float bf2f(short b) {
  return __uint_as_float(((unsigned)(unsigned short)b) << 16);
}
__device__ __forceinline__ u16t f2bf(float f) {
  unsigned u = __float_as_uint(f);
  u += 0x7FFFu + ((u >> 16) & 1u);  // RNE
  return (u16t)(u >> 16);
}

// jax threefry2x32, key = (0, 42)
__device__ __forceinline__ bool keep_mask(unsigned flat) {
  const unsigned k0 = 0u, k1 = 42u;
  const unsigned k2 = k0 ^ k1 ^ 0x1BD11BDAu;
  unsigned x0 = 0u + k0;
  unsigned x1 = flat + k1;
#define TF_R(r) { x0 += x1; x1 = (x1 << r) | (x1 >> (32 - r)); x1 ^= x0; }
  TF_R(13) TF_R(15) TF_R(26) TF_R(6)  x0 += k1; x1 += k2 + 1u;
  TF_R(17) TF_R(29) TF_R(16) TF_R(24) x0 += k2; x1 += k0 + 2u;
  TF_R(13) TF_R(15) TF_R(26) TF_R(6)  x0 += k0; x1 += k1 + 3u;
  TF_R(17) TF_R(29) TF_R(16) TF_R(24) x0 += k1; x1 += k2 + 4u;
  TF_R(13) TF_R(15) TF_R(26) TF_R(6)  x0 += k2; x1 += k0 + 5u;
#undef TF_R
  return ((x0 ^ x1) >> 31) == 0u;
}

__device__ __forceinline__ void load_lds16(const u16t* g, u16t* l) {
  __builtin_amdgcn_global_load_lds((__attribute__((address_space(1))) void*)g,
                                   (__attribute__((address_space(3))) void*)l,
                                   16, 0, 0);
}

// ---- f32 -> bf16 conversion ----
__global__ void cvt_bf16(const float* __restrict__ s, u16t* __restrict__ d, int n) {
  int i = (blockIdx.x * 256 + threadIdx.x) * 4;
  if (i < n) {
    f32x4 v = *(const f32x4*)&s[i];
    u16x4 o = { f2bf(v.x), f2bf(v.y), f2bf(v.z), f2bf(v.w) };
    *(u16x4*)&d[i] = o;
  }
}

// ---- f32 -> bf16 for x, FUSED threefry mask precompute (hidden under the
// 150MB cvt stream); mask is SLICE-MAJOR: mask[sl*nn + node].
__global__ __launch_bounds__(256) void cvt_x_mask(const float* __restrict__ s,
    u16t* __restrict__ d, unsigned* __restrict__ mask, int n, int nn) {
  int t = blockIdx.x * 256 + threadIdx.x;
  int i = t * 4;
  if (i < n) {
    f32x4 v = *(const f32x4*)&s[i];
    u16x4 o = { f2bf(v.x), f2bf(v.y), f2bf(v.z), f2bf(v.w) };
    *(u16x4*)&d[i] = o;
  }
  if (t < nn * 16) {
    unsigned base = (unsigned)t * 32u;
    unsigned m = 0u;
    for (int k = 0; k < 32; ++k) m |= (keep_mask(base + (unsigned)k) ? 1u : 0u) << k;
    mask[(size_t)(t & 15) * nn + (t >> 4)] = m;
  }
}

// ---- CSR build ----
__global__ void count_edges(const int* __restrict__ dst, int E, int* __restrict__ cnt) {
  int e = blockIdx.x * 256 + threadIdx.x;
  if (e < E) atomicAdd(&cnt[dst[e]], 1);
}

// Degree-bin histogram, LDS-aggregated: 16 global atomics per BLOCK.
__global__ __launch_bounds__(256) void bin_hist(const int* __restrict__ cnt,
                                                int* __restrict__ hist, int n) {
  __shared__ int sh[16];
  const int tid = threadIdx.x;
  if (tid < 16) sh[tid] = 0;
  __syncthreads();
  int i = blockIdx.x * 256 + tid;
  if (i < n) {
    int b = (cnt[i] + 8) >> 3;
    atomicAdd(&sh[b < 15 ? b : 15], 1);
  }
  __syncthreads();
  if (tid < 16 && sh[tid] > 0) atomicAdd(&hist[tid], sh[tid]);
}

// DESCENDING bin bases (LPT): longest propagate blocks dispatch first.
__global__ void bin_scan(const int* __restrict__ hist, int* __restrict__ binCursor) {
  if (threadIdx.x == 0 && blockIdx.x == 0) {
    int s = 0;
    for (int b = 15; b >= 0; --b) { binCursor[b] = s; s += hist[b]; }
  }
}

// Padded CSR row build + degree-bin permutation (LDS-aggregated bin ranks).
__global__ __launch_bounds__(256) void rowp_build(const int* __restrict__ cnt,
    i32x4* __restrict__ ndr, int* __restrict__ cursor, float* __restrict__ dinv,
    int* __restrict__ gctr, u16t* __restrict__ colu,
    int* __restrict__ binCursor, u16t* __restrict__ perm, int n) {
  __shared__ int sd[256];
  __shared__ int sbase;
  __shared__ int shist[16];
  __shared__ int sbinbase[16];
  const int tid = threadIdx.x;
  const int i = blockIdx.x * 256 + tid;
  int c = (i < n) ? cnt[i] : 0;
  int cs = c + 1;
  int p = (i < n) ? ((cs + 7) & ~7) : 0;
  int v = p;
  sd[tid] = v;
  if (tid < 16) shist[tid] = 0;
  __syncthreads();
  for (int o = 1; o < 256; o <<= 1) {
    int t2 = (tid >= o) ? sd[tid - o] : 0;
    __syncthreads();
    v += t2;
    sd[tid] = v;
    __syncthreads();
  }
  int b = p >> 3;
  b = b < 15 ? b : 15;
  int rank = 0;
  if (i < n) rank = atomicAdd(&shist[b], 1);
  if (tid == 255) sbase = atomicAdd(gctr, v);
  __syncthreads();
  if (tid < 16) sbinbase[tid] = (shist[tid] > 0) ? atomicAdd(&binCursor[tid], shist[tid]) : 0;
  __syncthreads();
  if (i < n) {
    int start = sbase + v - p;
    cursor[i] = start;
    float dv = rsqrtf((float)cs);
    dinv[i] = dv;
    i32x4 r;
    r[0] = start; r[1] = start + p; r[2] = __float_as_int(dv); r[3] = 0;
    ndr[i] = r;
    colu[start + c] = (u16t)i;                                  // self entry
    for (int q = c + 1; q < p; ++q) colu[start + q] = (u16t)n;  // dummies -> zero row
    perm[sbinbase[b] + rank] = (u16t)i;
  }
}

__global__ void fill_csr(const int* __restrict__ src, const int* __restrict__ dst, int E,
                         int* __restrict__ cursor, u16t* __restrict__ col) {
  int e = blockIdx.x * 256 + threadIdx.x;
  if (e < E) {
    int d = dst[e];
    int pos = atomicAdd(&cursor[d], 1);
    col[pos] = (u16t)src[e];
  }
}

// ---- bf16 GEMM, SLICE-MAJOR output, rows PRE-SCALED by dinv[row];
// rows >= Nclamp written as exact zeros (zero row for CSR dummies).
__global__ __launch_bounds__(256) void gemm_bt_sl(const u16t* __restrict__ A,
                                                  const u16t* __restrict__ B,
                                                  u16t* __restrict__ C,
                                                  int K, int Mrows,
                                                  const float* __restrict__ dinv,
                                                  int Nclamp) {
  __shared__ __align__(16) u16t lA[128 * 32];
  __shared__ __align__(16) u16t lB[128 * 32];
  const int tid = threadIdx.x;
  const int wave = tid >> 6, lane = tid & 63;
  const int wm = (wave & 1) * 64, wn = (wave >> 1) * 64;
  const int lrow = lane & 15, lq = lane >> 4;
  const u16t* Ab = A + (size_t)blockIdx.x * 128 * K;
  const u16t* Bb = B + (size_t)blockIdx.y * 128 * K;
  const int r0 = tid >> 2, c0 = (tid & 3) * 8;
  const int ldsOff = __builtin_amdgcn_readfirstlane((tid >> 6) * 512);

  f32x4 acc[4][4];
  const f32x4 zero = {0.f, 0.f, 0.f, 0.f};
#pragma unroll
  for (int mi = 0; mi < 4; ++mi)
#pragma unroll
    for (int ni = 0; ni < 4; ++ni) acc[mi][ni] = zero;

  for (int kt = 0; kt < K; kt += 32) {
    __syncthreads();
    load_lds16(Ab + (size_t)r0 * K + kt + c0, &lA[ldsOff]);
    load_lds16(Ab + (size_t)(r0 + 64) * K + kt + c0, &lA[2048 + ldsOff]);
    load_lds16(Bb + (size_t)r0 * K + kt + c0, &lB[ldsOff]);
    load_lds16(Bb + (size_t)(r0 + 64) * K + kt + c0, &lB[2048 + ldsOff]);
    __syncthreads();
    short8 af[4], bfr[4];
#pragma unroll
    for (int mi = 0; mi < 4; ++mi)
      af[mi] = *(const short8*)&lA[(wm + mi * 16 + lrow) * 32 + lq * 8];
#pragma unroll
    for (int ni = 0; ni < 4; ++ni)
      bfr[ni] = *(const short8*)&lB[(wn + ni * 16 + lrow) * 32 + lq * 8];
#pragma unroll
    for (int mi = 0; mi < 4; ++mi)
#pragma unroll
      for (int ni = 0; ni < 4; ++ni)
        acc[mi][ni] = __builtin_amdgcn_mfma_f32_16x16x32_bf16(af[mi], bfr[ni], acc[mi][ni], 0, 0, 0);
  }

  const int crow0 = blockIdx.x * 128 + wm + lq * 4;
  const int ccol0 = blockIdx.y * 128 + wn + lrow;
#pragma unroll
  for (int mi = 0; mi < 4; ++mi)
#pragma unroll
    for (int r = 0; r < 4; ++r) {
      const int row = crow0 + mi * 16 + r;
      const float dr = (row < Nclamp) ? dinv[row] : 0.f;
#pragma unroll
      for (int ni = 0; ni < 4; ++ni) {
        int cc = ccol0 + ni * 16;
        size_t idx = ((size_t)(cc >> 5) * Mrows + row) * 32 + (cc & 31);
        C[idx] = f2bf(dr * acc[mi][ni][r]);
      }
    }
}

// Issue the 8 x dwordx4 gathers for one 8-edge chunk (no consume).
__device__ __forceinline__ void load8(const char* __restrict__ Tb, u32x4 cw,
                                      unsigned flb, u32x4 w[8]) {
  unsigned off[8];
#pragma unroll
  for (int q = 0; q < 4; ++q) {
    off[2 * q]     = ((cw[q] & 0xFFFFu) << 6) | flb;
    off[2 * q + 1] = ((cw[q] >> 16) << 6) | flb;
  }
#pragma unroll
  for (int q = 0; q < 8; ++q) w[q] = *(const u32x4*)(Tb + (size_t)off[q]);
}

// Consume one chunk: unpack bf16 pairs, packed f32x2 adds.
__device__ __forceinline__ void accum8(const u32x4 w[8], f32x2 acc[4]) {
#pragma unroll
  for (int q = 0; q < 8; ++q)
#pragma unroll
    for (int d = 0; d < 4; ++d) {
      f32x2 v = { __uint_as_float(w[q][d] << 16),
                  __uint_as_float(w[q][d] & 0xFFFF0000u) };
      acc[d] += v;
    }
}

// ---- sliced propagate layer 1: 4 lanes/node (16B each), 64 nodes/block,
// LPT degree-binned order, padded CSR, 2-DEEP pipelined gathers (16 lines
// in flight per wave: chunk k+1's loads issue before chunk k is consumed).
__global__ __launch_bounds__(256) void prop1_kernel(const u16t* __restrict__ T0,
    const u16t* __restrict__ colu, const i32x4* __restrict__ ndr,
    const u16t* __restrict__ perm, const float* __restrict__ b1,
    const unsigned* __restrict__ kmask,
    float* __restrict__ embf, u16t* __restrict__ embb, int n, int Mrows, int chunks) {
  const int t = threadIdx.x;
  const unsigned flb = (unsigned)(t & 3) * 16u;  // byte offset of lane's 8 feats
  const int fl8 = (t & 3) * 8;
  const int bid = blockIdx.x;
  const int half = chunks << 3;
  const int phase = bid >= half;
  const int rem = bid - (phase ? half : 0);
  const int sl = (rem & 7) + (phase << 3);
  const int slot = (rem >> 3) * 64 + (t >> 2);
  if (slot >= n) return;
  const int i = (int)perm[slot];

  const char* Tb = (const char*)T0 + (size_t)sl * ((size_t)Mrows * 64);
  const i32x4 nd = ndr[i];
  const float di = __int_as_float(nd[2]);
  f32x2 a[4] = {{0.f, 0.f}, {0.f, 0.f}, {0.f, 0.f}, {0.f, 0.f}};

  int e = nd[0];
  const int end = nd[1];
  u32x4 w0[8], w1[8];
  {
    u32x4 cw = *(const u32x4*)&colu[e];
    load8(Tb, cw, flb, w0);
  }
  e += 8;
  if (e >= end) {
    accum8(w0, a);
  } else {
    {
      u32x4 cw = *(const u32x4*)&colu[e];
      load8(Tb, cw, flb, w1);
    }
    e += 8;
    for (;;) {
      accum8(w0, a);
      if (e >= end) { accum8(w1, a); break; }
      {
        u32x4 cw = *(const u32x4*)&colu[e];
        load8(Tb, cw, flb, w0);
      }
      e += 8;
      accum8(w1, a);
      if (e >= end) { accum8(w0, a); break; }
      {
        u32x4 cw = *(const u32x4*)&colu[e];
        load8(Tb, cw, flb, w1);
      }
      e += 8;
    }
  }

  const int f = sl * 32 + fl8;
  const unsigned km = kmask[(size_t)sl * n + i] >> fl8;
  float acc[8] = {a[0].x, a[0].y, a[1].x, a[1].y, a[2].x, a[2].y, a[3].x, a[3].y};
  f32x4 o0, o1;
  short8 ob;
#pragma unroll
  for (int j = 0; j < 8; ++j) {
    float h = di * acc[j] + b1[f + j];
    h = fmaxf(h, 0.f);
    float eb = ((km >> j) & 1u) ? 2.f * h : 0.f;
    if (j < 4) o0[j] = eb; else o1[j - 4] = eb;
    ob[j] = (short)f2bf(eb);
  }
  __builtin_nontemporal_store(o0, (f32x4*)&embf[(size_t)i * 512 + f]);
  __builtin_nontemporal_store(o1, (f32x4*)&embf[(size_t)i * 512 + f + 4]);
  __builtin_nontemporal_store(ob, (short8*)&embb[(size_t)i * 512 + f]);
}

// ---- sliced propagate layer 2 (8 slices, 1 phase), same pipeline ----
__global__ __launch_bounds__(256) void prop2_kernel(const u16t* __restrict__ T0,
    const u16t* __restrict__ colu, const i32x4* __restrict__ ndr,
    const u16t* __restrict__ perm, const float* __restrict__ b2,
    float* __restrict__ outp, int n, int Mrows) {
  const int t = threadIdx.x;
  const unsigned flb = (unsigned)(t & 3) * 16u;
  const int fl8 = (t & 3) * 8;
  const int bid = blockIdx.x;
  const int sl = bid & 7;
  const int slot = (bid >> 3) * 64 + (t >> 2);
  if (slot >= n) return;
  const int i = (int)perm[slot];

  const char* Tb = (const char*)T0 + (size_t)sl * ((size_t)Mrows * 64);
  const i32x4 nd = ndr[i];
  const float di = __int_as_float(nd[2]);
  f32x2 a[4] = {{0.f, 0.f}, {0.f, 0.f}, {0.f, 0.f}, {0.f, 0.f}};

  int e = nd[0];
  const int end = nd[1];
  u32x4 w0[8], w1[8];
  {
    u32x4 cw = *(const u32x4*)&colu[e];
    load8(Tb, cw, flb, w0);
  }
  e += 8;
  if (e >= end) {
    accum8(w0, a);
  } else {
    {
      u32x4 cw = *(const u32x4*)&colu[e];
      load8(Tb, cw, flb, w1);
    }
    e += 8;
    for (;;) {
      accum8(w0, a);
      if (e >= end) { accum8(w1, a); break; }
      {
        u32x4 cw = *(const u32x4*)&colu[e];
        load8(Tb, cw, flb, w0);
      }
      e += 8;
      accum8(w1, a);
      if (e >= end) { accum8(w0, a); break; }
      {
        u32x4 cw = *(const u32x4*)&colu[e];
        load8(Tb, cw, flb, w1);
      }
      e += 8;
    }
  }

  const int f = sl * 32 + fl8;
  float acc[8] = {a[0].x, a[0].y, a[1].x, a[1].y, a[2].x, a[2].y, a[3].x, a[3].y};
  f32x4 o0, o1;
#pragma unroll
  for (int j = 0; j < 8; ++j) {
    float v = di * acc[j] + b2[f + j];
    if (j < 4) o0[j] = v; else o1[j - 4] = v;
  }
  __builtin_nontemporal_store(o0, (f32x4*)&outp[(size_t)i * 256 + f]);
  __builtin_nontemporal_store(o1, (f32x4*)&outp[(size_t)i * 256 + f + 4]);
}

extern "C" void kernel_launch(void* const* d_in, const int* in_sizes, int n_in,
                              void* d_out, int out_size, void* d_ws, size_t ws_size,
                              hipStream_t stream) {
  (void)n_in; (void)out_size; (void)ws_size;
  const float* x  = (const float*)d_in[0];
  const int*   ei = (const int*)d_in[1];    // [2][E]: src row then dst row
  const float* W1 = (const float*)d_in[2];
  const float* b1 = (const float*)d_in[3];
  const float* W2 = (const float*)d_in[4];
  const float* b2 = (const float*)d_in[5];

  const int Nn = in_sizes[0] / 512;             // 50000
  const int E  = in_sizes[1] / 2;               // 800000
  const int Mpad = ((Nn + 127) / 128) * 128;    // 50048
  const int K = 512;
  const int CH = (Nn + 63) / 64;                // 64 nodes per slice-block

  char* ws = (char*)d_ws;
  size_t off = 0;
  auto take = [&](size_t bytes) -> char* {
    char* p = ws + off;
    off += (bytes + 255) & ~(size_t)255;
    return p;
  };
  u16t* xb   = (u16t*)take((size_t)Mpad * 512 * 2);      // x bf16; reused as emb bf16
  u16t* y1s  = (u16t*)take((size_t)16 * Mpad * 32 * 2);  // y1 slice-major; zs aliases
  u16t* W1b  = (u16t*)take((size_t)512 * 512 * 2);
  u16t* W2b  = (u16t*)take((size_t)256 * 512 * 2);
  // cnt[Nn] | gctr | hist[16] | binCursor[16]
  int*   cnt    = (int*)take((size_t)(Nn + 33) * 4);
  int*   cursor = (int*)take((size_t)Nn * 4);
  float* dinv   = (float*)take((size_t)Nn * 4);
  i32x4* ndr    = (i32x4*)take((size_t)Nn * 16);         // {start, end, dinv, 0}
  u16t*  perm   = (u16t*)take((size_t)Nn * 2);           // LPT degree-binned order
  u16t*  colu   = (u16t*)take((size_t)(E + 8 * (Nn + 1) + 64) * 2);  // padded CSR
  unsigned* kmask = (unsigned*)take((size_t)Nn * 16 * 4);  // slice-major keep bits

  float* embf = (float*)d_out;                       // [Nn,512]
  float* outf = (float*)d_out + (size_t)Nn * 512;    // [Nn,256]

  int* gctr      = cnt + Nn;
  int* hist      = cnt + Nn + 1;
  int* binCursor = cnt + Nn + 17;

  hipMemsetAsync(cnt, 0, (size_t)(Nn + 33) * 4, stream);

  const int n1 = Nn * 512;
  cvt_x_mask<<<(n1 / 4 + 255) / 256, 256, 0, stream>>>(x, xb, kmask, n1, Nn);
  cvt_bf16<<<(512 * 512 / 4 + 255) / 256, 256, 0, stream>>>(W1, W1b, 512 * 512);
  cvt_bf16<<<(256 * 512 / 4 + 255) / 256, 256, 0, stream>>>(W2, W2b, 256 * 512);

  count_edges<<<(E + 255) / 256, 256, 0, stream>>>(ei + E, E, cnt);
  bin_hist<<<(Nn + 255) / 256, 256, 0, stream>>>(cnt, hist, Nn);
  bin_scan<<<1, 64, 0, stream>>>(hist, binCursor);
  rowp_build<<<(Nn + 255) / 256, 256, 0, stream>>>(cnt, ndr, cursor, dinv, gctr,
                                                   colu, binCursor, perm, Nn);
  fill_csr<<<(E + 255) / 256, 256, 0, stream>>>(ei, ei + E, E, cursor, colu);

  // layer 1: y1 = dinv * (x @ W1^T), slice-major; then XCD-sliced propagate
  dim3 g1(Mpad / 128, 4);
  gemm_bt_sl<<<g1, 256, 0, stream>>>(xb, W1b, y1s, K, Mpad, dinv, Nn);
  prop1_kernel<<<16 * CH, 256, 0, stream>>>(y1s, colu, ndr, perm, b1, kmask,
                                            embf, xb /* emb bf16 */, Nn, Mpad, CH);

  // layer 2: z = dinv * (emb @ W2^T), slice-major; then propagate + b2
  u16t* zs = y1s;  // alias: y1 dead after prop1
  dim3 g2(Mpad / 128, 2);
  gemm_bt_sl<<<g2, 256, 0, stream>>>(xb, W2b, zs, K, Mpad, dinv, Nn);
  prop2_kernel<<<8 * CH, 256, 0, stream>>>(zs, colu, ndr, perm, b2, outf, Nn, Mpad);
}